// Round 1
// baseline (3396.595 us; speedup 1.0000x reference)
//
#include <hip/hip_runtime.h>
#include <math.h>

#define NNODE 200000
#define NEDGE 1000000
#define HEDGE 500000

// ---- float <-> monotone uint key (for atomicMax on floats) ----
__device__ __forceinline__ unsigned fkey(float f) {
  unsigned b = __float_as_uint(f);
  return (b & 0x80000000u) ? ~b : (b | 0x80000000u);
}
__device__ __forceinline__ float funkey(unsigned k) {
  unsigned b = (k & 0x80000000u) ? (k ^ 0x80000000u) : ~k;
  return __uint_as_float(b);
}

// ---- segment_sum(emb, dst) over all edges ----
__global__ void k_aggr(const int* __restrict__ ei, const float* __restrict__ emb,
                       float* __restrict__ aggr) {
  int tid = blockIdx.x * 256 + threadIdx.x;
  if (tid >= NEDGE * 64) return;
  int e = tid >> 6, c = tid & 63;
  int d = ei[2 * e + 1];
  atomicAdd(&aggr[d * 64 + c], emb[tid]);
}

// ---- segment_max(e, c2l_src) ----
__global__ void k_cmax(const int* __restrict__ ei, const int* __restrict__ c2li,
                       const float* __restrict__ emb, unsigned* __restrict__ mkey) {
  int tid = blockIdx.x * 256 + threadIdx.x;
  if (tid >= HEDGE * 64) return;
  int i = tid >> 6, c = tid & 63;
  int j = c2li[i];
  int s = ei[2 * j], d = ei[2 * j + 1];
  float v = emb[d * 64 + c];
  atomicMax(&mkey[s * 64 + c], fkey(v));
}

// ---- segment_sum(exp(e - m)) ----
__global__ void k_cexp(const int* __restrict__ ei, const int* __restrict__ c2li,
                       const float* __restrict__ emb, const unsigned* __restrict__ mkey,
                       float* __restrict__ ssum) {
  int tid = blockIdx.x * 256 + threadIdx.x;
  if (tid >= HEDGE * 64) return;
  int i = tid >> 6, c = tid & 63;
  int j = c2li[i];
  int s = ei[2 * j], d = ei[2 * j + 1];
  float v = emb[d * 64 + c];
  float m = funkey(mkey[s * 64 + c]);  // this segment is non-empty (we contributed)
  atomicAdd(&ssum[s * 64 + c], expf(v - m));
}

// ---- lse = log(ssum>0 ? ssum : 1) + (finite m ? m : 0), written over ssum ----
__global__ void k_lse(const unsigned* __restrict__ mkey, float* __restrict__ ssum) {
  int tid = blockIdx.x * 256 + threadIdx.x;
  if (tid >= NNODE * 64) return;
  unsigned k = mkey[tid];
  float ss = ssum[tid];
  float m = (k == 0u) ? 0.f : funkey(k);
  float l = (ss > 0.f) ? logf(ss) : 0.f;
  ssum[tid] = l + m;
}

// ---- 64x64 dense layer, activations in registers, W from (hopefully) s_load ----
template <bool RELU>
__device__ __forceinline__ void layer64(const float* __restrict__ W, const float* __restrict__ b,
                                        const float (&x)[64], float (&y)[64]) {
#pragma unroll
  for (int c4 = 0; c4 < 16; ++c4) {
    float a0 = b[4 * c4 + 0], a1 = b[4 * c4 + 1], a2 = b[4 * c4 + 2], a3 = b[4 * c4 + 3];
#pragma unroll
    for (int k = 0; k < 64; ++k) {
      float xv = x[k];
      const float* wr = W + k * 64 + 4 * c4;
      a0 = fmaf(xv, wr[0], a0);
      a1 = fmaf(xv, wr[1], a1);
      a2 = fmaf(xv, wr[2], a2);
      a3 = fmaf(xv, wr[3], a3);
    }
    if (RELU) {
      a0 = fmaxf(a0, 0.f); a1 = fmaxf(a1, 0.f); a2 = fmaxf(a2, 0.f); a3 = fmaxf(a3, 0.f);
    }
    y[4 * c4 + 0] = a0; y[4 * c4 + 1] = a1; y[4 * c4 + 2] = a2; y[4 * c4 + 3] = a3;
  }
}

// ---- merge layer: x[c] = relu( b[c] + msg.W0top[:,c] + msg_partner.W0bot[:,c] ) ----
// partner (lane^1) contribution fetched by shuffling the *partial sums*.
__device__ __forceinline__ void merge0(const float* __restrict__ W, const float* __restrict__ b,
                                       const float (&msg)[64], float (&x)[64]) {
#pragma unroll
  for (int c4 = 0; c4 < 16; ++c4) {
    float a0 = b[4 * c4 + 0], a1 = b[4 * c4 + 1], a2 = b[4 * c4 + 2], a3 = b[4 * c4 + 3];
    float t0 = 0.f, t1 = 0.f, t2 = 0.f, t3 = 0.f;
#pragma unroll
    for (int k = 0; k < 64; ++k) {
      float xv = msg[k];
      const float* wt = W + k * 64 + 4 * c4;         // rows [0,64): own msg
      const float* wb = W + (64 + k) * 64 + 4 * c4;  // rows [64,128): partner msg
      a0 = fmaf(xv, wt[0], a0);
      a1 = fmaf(xv, wt[1], a1);
      a2 = fmaf(xv, wt[2], a2);
      a3 = fmaf(xv, wt[3], a3);
      t0 = fmaf(xv, wb[0], t0);
      t1 = fmaf(xv, wb[1], t1);
      t2 = fmaf(xv, wb[2], t2);
      t3 = fmaf(xv, wb[3], t3);
    }
    x[4 * c4 + 0] = fmaxf(a0 + __shfl_xor(t0, 1), 0.f);
    x[4 * c4 + 1] = fmaxf(a1 + __shfl_xor(t1, 1), 0.f);
    x[4 * c4 + 2] = fmaxf(a2 + __shfl_xor(t2, 1), 0.f);
    x[4 * c4 + 3] = fmaxf(a3 + __shfl_xor(t3, 1), 0.f);
  }
}

// ---- l2c branch: 3-layer MLP -> pair merge -> 2-layer MLP, lane = row ----
__global__ void k_l2c(const int* __restrict__ ei, const int* __restrict__ l2ci,
                      const float* __restrict__ emb, const float* __restrict__ aggr,
                      const float* __restrict__ W, const float* __restrict__ bb,
                      const float* __restrict__ mW0, const float* __restrict__ mb0,
                      const float* __restrict__ mW, const float* __restrict__ mb,
                      float* __restrict__ out) {
  int r = blockIdx.x * 256 + threadIdx.x;
  int rc = r < HEDGE ? r : HEDGE - 1;  // no early return: shfl needs the full wave
  int j = l2ci[rc];
  int s = ei[2 * j], d = ei[2 * j + 1];
  const float4* ap = (const float4*)(aggr + s * 64);
  const float4* ep = (const float4*)(emb + d * 64);
  float x[64], y[64];
#pragma unroll
  for (int q = 0; q < 16; ++q) {
    float4 a = ap[q], e = ep[q];
    x[4 * q + 0] = a.x - e.x;
    x[4 * q + 1] = a.y - e.y;
    x[4 * q + 2] = a.z - e.z;
    x[4 * q + 3] = a.w - e.w;
  }
  layer64<true>(W, bb, x, y);
  layer64<true>(W + 4096, bb + 64, y, x);
  layer64<false>(W + 8192, bb + 128, x, y);  // y = l2c_msg
  merge0(mW0, mb0, y, x);                    // x = relu(cat @ merge_W0 + b0)
  layer64<true>(mW, mb, x, y);
  layer64<false>(mW + 4096, mb + 64, y, x);
  if (r < HEDGE) {
    float4* op = (float4*)(out + j * 64);
#pragma unroll
    for (int q = 0; q < 16; ++q) {
      float4 v;
      v.x = x[4 * q + 0]; v.y = x[4 * q + 1]; v.z = x[4 * q + 2]; v.w = x[4 * q + 3];
      op[q] = v;
    }
  }
}

// ---- c2l branch: 3-layer MLP on (lse[src] - e), lane = row ----
__global__ void k_c2l(const int* __restrict__ ei, const int* __restrict__ c2li,
                      const float* __restrict__ emb, const float* __restrict__ lse,
                      const float* __restrict__ W, const float* __restrict__ bb,
                      float* __restrict__ out) {
  int r = blockIdx.x * 256 + threadIdx.x;
  if (r >= HEDGE) return;
  int j = c2li[r];
  int s = ei[2 * j], d = ei[2 * j + 1];
  const float4* lp = (const float4*)(lse + s * 64);
  const float4* ep = (const float4*)(emb + d * 64);
  float x[64], y[64];
#pragma unroll
  for (int q = 0; q < 16; ++q) {
    float4 a = lp[q], e = ep[q];
    x[4 * q + 0] = a.x - e.x;
    x[4 * q + 1] = a.y - e.y;
    x[4 * q + 2] = a.z - e.z;
    x[4 * q + 3] = a.w - e.w;
  }
  layer64<true>(W, bb, x, y);
  layer64<true>(W + 4096, bb + 64, y, x);
  layer64<false>(W + 8192, bb + 128, x, y);
  float4* op = (float4*)(out + j * 64);
#pragma unroll
  for (int q = 0; q < 16; ++q) {
    float4 v;
    v.x = y[4 * q + 0]; v.y = y[4 * q + 1]; v.z = y[4 * q + 2]; v.w = y[4 * q + 3];
    op[q] = v;
  }
}

extern "C" void kernel_launch(void* const* d_in, const int* in_sizes, int n_in,
                              void* d_out, int out_size, void* d_ws, size_t ws_size,
                              hipStream_t stream) {
  const int* ei = (const int*)d_in[0];
  const int* l2ci = (const int*)d_in[1];
  const int* c2li = (const int*)d_in[2];
  const float* emb = (const float*)d_in[3];
  const float* l2cW = (const float*)d_in[4];
  const float* l2cb = (const float*)d_in[5];
  const float* c2lW = (const float*)d_in[6];
  const float* c2lb = (const float*)d_in[7];
  const float* mW0 = (const float*)d_in[8];
  const float* mb0 = (const float*)d_in[9];
  const float* mW = (const float*)d_in[10];
  const float* mb = (const float*)d_in[11];
  float* out = (float*)d_out;

  char* ws = (char*)d_ws;
  const size_t NB = (size_t)NNODE * 64 * 4;  // 51.2 MB per node-buffer
  float* aggr = (float*)ws;
  unsigned* mkey = (unsigned*)(ws + NB);
  float* ssum = (float*)(ws + 2 * NB);  // becomes lse in-place

  hipMemsetAsync(d_ws, 0, 3 * NB, stream);  // aggr=0, mkey=0 (== -inf key), ssum=0

  dim3 B(256);
  k_aggr<<<(NEDGE * 64 + 255) / 256, B, 0, stream>>>(ei, emb, aggr);
  k_cmax<<<(HEDGE * 64 + 255) / 256, B, 0, stream>>>(ei, c2li, emb, mkey);
  k_cexp<<<(HEDGE * 64 + 255) / 256, B, 0, stream>>>(ei, c2li, emb, mkey, ssum);
  k_lse<<<(NNODE * 64 + 255) / 256, B, 0, stream>>>(mkey, ssum);
  k_l2c<<<(HEDGE + 255) / 256, B, 0, stream>>>(ei, l2ci, emb, aggr, l2cW, l2cb, mW0, mb0, mW, mb, out);
  k_c2l<<<(HEDGE + 255) / 256, B, 0, stream>>>(ei, c2li, emb, ssum, c2lW, c2lb, out);
}

// Round 2
// 2227.240 us; speedup vs baseline: 1.5250x; 1.5250x over previous
//
#include <hip/hip_runtime.h>
#include <math.h>

#define NNODE 200000
#define NEDGE 1000000
#define HEDGE 500000

// ---- float <-> monotone uint key (for atomicMax on floats) ----
__device__ __forceinline__ unsigned fkey(float f) {
  unsigned b = __float_as_uint(f);
  return (b & 0x80000000u) ? ~b : (b | 0x80000000u);
}
__device__ __forceinline__ float funkey(unsigned k) {
  unsigned b = (k & 0x80000000u) ? (k ^ 0x80000000u) : ~k;
  return __uint_as_float(b);
}

// ---- segment_sum(emb, dst) over all edges ----
__global__ void k_aggr(const int* __restrict__ ei, const float* __restrict__ emb,
                       float* __restrict__ aggr) {
  int tid = blockIdx.x * 256 + threadIdx.x;
  if (tid >= NEDGE * 64) return;
  int e = tid >> 6, c = tid & 63;
  int d = ei[2 * e + 1];
  atomicAdd(&aggr[d * 64 + c], emb[tid]);
}

// ---- segment_max(e, c2l_src) ----
__global__ void k_cmax(const int* __restrict__ ei, const int* __restrict__ c2li,
                       const float* __restrict__ emb, unsigned* __restrict__ mkey) {
  int tid = blockIdx.x * 256 + threadIdx.x;
  if (tid >= HEDGE * 64) return;
  int i = tid >> 6, c = tid & 63;
  int j = c2li[i];
  int s = ei[2 * j], d = ei[2 * j + 1];
  float v = emb[d * 64 + c];
  atomicMax(&mkey[s * 64 + c], fkey(v));
}

// ---- segment_sum(exp(e - m)) ----
__global__ void k_cexp(const int* __restrict__ ei, const int* __restrict__ c2li,
                       const float* __restrict__ emb, const unsigned* __restrict__ mkey,
                       float* __restrict__ ssum) {
  int tid = blockIdx.x * 256 + threadIdx.x;
  if (tid >= HEDGE * 64) return;
  int i = tid >> 6, c = tid & 63;
  int j = c2li[i];
  int s = ei[2 * j], d = ei[2 * j + 1];
  float v = emb[d * 64 + c];
  float m = funkey(mkey[s * 64 + c]);  // this segment is non-empty (we contributed)
  atomicAdd(&ssum[s * 64 + c], expf(v - m));
}

// ---- lse = log(ssum>0 ? ssum : 1) + (finite m ? m : 0), written over ssum ----
__global__ void k_lse(const unsigned* __restrict__ mkey, float* __restrict__ ssum) {
  int tid = blockIdx.x * 256 + threadIdx.x;
  if (tid >= NNODE * 64) return;
  unsigned k = mkey[tid];
  float ss = ssum[tid];
  float m = (k == 0u) ? 0.f : funkey(k);
  float l = (ss > 0.f) ? logf(ss) : 0.f;
  ssum[tid] = l + m;
}

// ---- 64x64 dense layer, activations in registers, W via scalar loads ----
template <bool RELU>
__device__ __forceinline__ void layer64(const float* __restrict__ W, const float* __restrict__ b,
                                        const float (&x)[64], float (&y)[64]) {
#pragma unroll
  for (int c4 = 0; c4 < 16; ++c4) {
    float a0 = b[4 * c4 + 0], a1 = b[4 * c4 + 1], a2 = b[4 * c4 + 2], a3 = b[4 * c4 + 3];
#pragma unroll
    for (int k = 0; k < 64; ++k) {
      float xv = x[k];
      const float* wr = W + k * 64 + 4 * c4;
      a0 = fmaf(xv, wr[0], a0);
      a1 = fmaf(xv, wr[1], a1);
      a2 = fmaf(xv, wr[2], a2);
      a3 = fmaf(xv, wr[3], a3);
    }
    if (RELU) {
      a0 = fmaxf(a0, 0.f); a1 = fmaxf(a1, 0.f); a2 = fmaxf(a2, 0.f); a3 = fmaxf(a3, 0.f);
    }
    y[4 * c4 + 0] = a0; y[4 * c4 + 1] = a1; y[4 * c4 + 2] = a2; y[4 * c4 + 3] = a3;
  }
}

// ---- merge layer: x[c] = relu( b[c] + msg.W0top[:,c] + msg_partner.W0bot[:,c] ) ----
// partner (lane^1) contribution fetched by shuffling the *partial sums*.
__device__ __forceinline__ void merge0(const float* __restrict__ W, const float* __restrict__ b,
                                       const float (&msg)[64], float (&x)[64]) {
#pragma unroll
  for (int c4 = 0; c4 < 16; ++c4) {
    float a0 = b[4 * c4 + 0], a1 = b[4 * c4 + 1], a2 = b[4 * c4 + 2], a3 = b[4 * c4 + 3];
    float t0 = 0.f, t1 = 0.f, t2 = 0.f, t3 = 0.f;
#pragma unroll
    for (int k = 0; k < 64; ++k) {
      float xv = msg[k];
      const float* wt = W + k * 64 + 4 * c4;         // rows [0,64): own msg
      const float* wb = W + (64 + k) * 64 + 4 * c4;  // rows [64,128): partner msg
      a0 = fmaf(xv, wt[0], a0);
      a1 = fmaf(xv, wt[1], a1);
      a2 = fmaf(xv, wt[2], a2);
      a3 = fmaf(xv, wt[3], a3);
      t0 = fmaf(xv, wb[0], t0);
      t1 = fmaf(xv, wb[1], t1);
      t2 = fmaf(xv, wb[2], t2);
      t3 = fmaf(xv, wb[3], t3);
    }
    x[4 * c4 + 0] = fmaxf(a0 + __shfl_xor(t0, 1), 0.f);
    x[4 * c4 + 1] = fmaxf(a1 + __shfl_xor(t1, 1), 0.f);
    x[4 * c4 + 2] = fmaxf(a2 + __shfl_xor(t2, 1), 0.f);
    x[4 * c4 + 3] = fmaxf(a3 + __shfl_xor(t3, 1), 0.f);
  }
}

// ---- l2c branch: 3-layer MLP -> pair merge -> 2-layer MLP, lane = row ----
// __launch_bounds__(256, 2): cap 256 VGPR/wave so x[64]+y[64] stay in registers
// (default heuristic capped at 64 VGPR -> full spill to scratch, 10x slowdown).
__global__ void __launch_bounds__(256, 2)
k_l2c(const int* __restrict__ ei, const int* __restrict__ l2ci,
      const float* __restrict__ emb, const float* __restrict__ aggr,
      const float* __restrict__ W, const float* __restrict__ bb,
      const float* __restrict__ mW0, const float* __restrict__ mb0,
      const float* __restrict__ mW, const float* __restrict__ mb,
      float* __restrict__ out) {
  int r = blockIdx.x * 256 + threadIdx.x;
  int rc = r < HEDGE ? r : HEDGE - 1;  // no early return: shfl needs the full wave
  int j = l2ci[rc];
  int s = ei[2 * j], d = ei[2 * j + 1];
  const float4* ap = (const float4*)(aggr + s * 64);
  const float4* ep = (const float4*)(emb + d * 64);
  float x[64], y[64];
#pragma unroll
  for (int q = 0; q < 16; ++q) {
    float4 a = ap[q], e = ep[q];
    x[4 * q + 0] = a.x - e.x;
    x[4 * q + 1] = a.y - e.y;
    x[4 * q + 2] = a.z - e.z;
    x[4 * q + 3] = a.w - e.w;
  }
  layer64<true>(W, bb, x, y);
  layer64<true>(W + 4096, bb + 64, y, x);
  layer64<false>(W + 8192, bb + 128, x, y);  // y = l2c_msg
  merge0(mW0, mb0, y, x);                    // x = relu(cat @ merge_W0 + b0)
  layer64<true>(mW, mb, x, y);
  layer64<false>(mW + 4096, mb + 64, y, x);
  if (r < HEDGE) {
    float4* op = (float4*)(out + j * 64);
#pragma unroll
    for (int q = 0; q < 16; ++q) {
      float4 v;
      v.x = x[4 * q + 0]; v.y = x[4 * q + 1]; v.z = x[4 * q + 2]; v.w = x[4 * q + 3];
      op[q] = v;
    }
  }
}

// ---- c2l branch: 3-layer MLP on (lse[src] - e), lane = row ----
__global__ void __launch_bounds__(256, 2)
k_c2l(const int* __restrict__ ei, const int* __restrict__ c2li,
      const float* __restrict__ emb, const float* __restrict__ lse,
      const float* __restrict__ W, const float* __restrict__ bb,
      float* __restrict__ out) {
  int r = blockIdx.x * 256 + threadIdx.x;
  if (r >= HEDGE) return;
  int j = c2li[r];
  int s = ei[2 * j], d = ei[2 * j + 1];
  const float4* lp = (const float4*)(lse + s * 64);
  const float4* ep = (const float4*)(emb + d * 64);
  float x[64], y[64];
#pragma unroll
  for (int q = 0; q < 16; ++q) {
    float4 a = lp[q], e = ep[q];
    x[4 * q + 0] = a.x - e.x;
    x[4 * q + 1] = a.y - e.y;
    x[4 * q + 2] = a.z - e.z;
    x[4 * q + 3] = a.w - e.w;
  }
  layer64<true>(W, bb, x, y);
  layer64<true>(W + 4096, bb + 64, y, x);
  layer64<false>(W + 8192, bb + 128, x, y);
  float4* op = (float4*)(out + j * 64);
#pragma unroll
  for (int q = 0; q < 16; ++q) {
    float4 v;
    v.x = y[4 * q + 0]; v.y = y[4 * q + 1]; v.z = y[4 * q + 2]; v.w = y[4 * q + 3];
    op[q] = v;
  }
}

extern "C" void kernel_launch(void* const* d_in, const int* in_sizes, int n_in,
                              void* d_out, int out_size, void* d_ws, size_t ws_size,
                              hipStream_t stream) {
  const int* ei = (const int*)d_in[0];
  const int* l2ci = (const int*)d_in[1];
  const int* c2li = (const int*)d_in[2];
  const float* emb = (const float*)d_in[3];
  const float* l2cW = (const float*)d_in[4];
  const float* l2cb = (const float*)d_in[5];
  const float* c2lW = (const float*)d_in[6];
  const float* c2lb = (const float*)d_in[7];
  const float* mW0 = (const float*)d_in[8];
  const float* mb0 = (const float*)d_in[9];
  const float* mW = (const float*)d_in[10];
  const float* mb = (const float*)d_in[11];
  float* out = (float*)d_out;

  char* ws = (char*)d_ws;
  const size_t NB = (size_t)NNODE * 64 * 4;  // 51.2 MB per node-buffer
  float* aggr = (float*)ws;
  unsigned* mkey = (unsigned*)(ws + NB);
  float* ssum = (float*)(ws + 2 * NB);  // becomes lse in-place

  hipMemsetAsync(d_ws, 0, 3 * NB, stream);  // aggr=0, mkey=0 (== -inf key), ssum=0

  dim3 B(256);
  k_aggr<<<(NEDGE * 64 + 255) / 256, B, 0, stream>>>(ei, emb, aggr);
  k_cmax<<<(HEDGE * 64 + 255) / 256, B, 0, stream>>>(ei, c2li, emb, mkey);
  k_cexp<<<(HEDGE * 64 + 255) / 256, B, 0, stream>>>(ei, c2li, emb, mkey, ssum);
  k_lse<<<(NNODE * 64 + 255) / 256, B, 0, stream>>>(mkey, ssum);
  k_l2c<<<(HEDGE + 255) / 256, B, 0, stream>>>(ei, l2ci, emb, aggr, l2cW, l2cb, mW0, mb0, mW, mb, out);
  k_c2l<<<(HEDGE + 255) / 256, B, 0, stream>>>(ei, c2li, emb, ssum, c2lW, c2lb, out);
}

// Round 3
// 1400.644 us; speedup vs baseline: 2.4250x; 1.5902x over previous
//
#include <hip/hip_runtime.h>
#include <math.h>

#define NNODE 200000
#define NEDGE 1000000
#define HEDGE 500000

// ---- float <-> monotone uint key (for atomicMax on floats) ----
__device__ __forceinline__ unsigned fkey(float f) {
  unsigned b = __float_as_uint(f);
  return (b & 0x80000000u) ? ~b : (b | 0x80000000u);
}
__device__ __forceinline__ float funkey(unsigned k) {
  unsigned b = (k & 0x80000000u) ? (k ^ 0x80000000u) : ~k;
  return __uint_as_float(b);
}

// ---- segment_sum(emb, dst) over all edges ----
__global__ void k_aggr(const int* __restrict__ ei, const float* __restrict__ emb,
                       float* __restrict__ aggr) {
  int tid = blockIdx.x * 256 + threadIdx.x;
  if (tid >= NEDGE * 64) return;
  int e = tid >> 6, c = tid & 63;
  int d = ei[2 * e + 1];
  atomicAdd(&aggr[d * 64 + c], emb[tid]);
}

// ---- segment_max(e, c2l_src) ----
__global__ void k_cmax(const int* __restrict__ ei, const int* __restrict__ c2li,
                       const float* __restrict__ emb, unsigned* __restrict__ mkey) {
  int tid = blockIdx.x * 256 + threadIdx.x;
  if (tid >= HEDGE * 64) return;
  int i = tid >> 6, c = tid & 63;
  int j = c2li[i];
  int s = ei[2 * j], d = ei[2 * j + 1];
  float v = emb[d * 64 + c];
  atomicMax(&mkey[s * 64 + c], fkey(v));
}

// ---- segment_sum(exp(e - m)) ----
__global__ void k_cexp(const int* __restrict__ ei, const int* __restrict__ c2li,
                       const float* __restrict__ emb, const unsigned* __restrict__ mkey,
                       float* __restrict__ ssum) {
  int tid = blockIdx.x * 256 + threadIdx.x;
  if (tid >= HEDGE * 64) return;
  int i = tid >> 6, c = tid & 63;
  int j = c2li[i];
  int s = ei[2 * j], d = ei[2 * j + 1];
  float v = emb[d * 64 + c];
  float m = funkey(mkey[s * 64 + c]);  // this segment is non-empty (we contributed)
  atomicAdd(&ssum[s * 64 + c], expf(v - m));
}

// ---- lse = log(ssum>0 ? ssum : 1) + (finite m ? m : 0), written over ssum ----
__global__ void k_lse(const unsigned* __restrict__ mkey, float* __restrict__ ssum) {
  int tid = blockIdx.x * 256 + threadIdx.x;
  if (tid >= NNODE * 64) return;
  unsigned k = mkey[tid];
  float ss = ssum[tid];
  float m = (k == 0u) ? 0.f : funkey(k);
  float l = (ss > 0.f) ? logf(ss) : 0.f;
  ssum[tid] = l + m;
}

// ============ LDS-activation MLP machinery ============
// Activations live in LDS as xs[k][t] (bank = t%32 -> 2 lanes/bank, free).
// Only the 64-float accumulator y[] lives in VGPRs. Weight rows are read at
// wave-uniform addresses -> s_load broadcast, VALU stays pure v_fmac_f32.

typedef float lds_t[256];

template <bool RELU>
__device__ __forceinline__ void layer_lds(const float* __restrict__ W, const float* __restrict__ b,
                                          lds_t* xs, int t, float (&y)[64]) {
#pragma unroll
  for (int c = 0; c < 64; ++c) y[c] = b[c];
#pragma unroll 2
  for (int k = 0; k < 64; ++k) {
    float xk = xs[k][t];
    const float* wr = W + k * 64;
#pragma unroll
    for (int c = 0; c < 64; ++c) y[c] = fmaf(xk, wr[c], y[c]);
  }
  if (RELU) {
#pragma unroll
    for (int c = 0; c < 64; ++c) y[c] = fmaxf(y[c], 0.f);
  }
}

// y -> xs (own column only; thread-local dependency, no barrier needed)
__device__ __forceinline__ void commit(lds_t* xs, int t, const float (&y)[64]) {
#pragma unroll
  for (int k = 0; k < 64; ++k) xs[k][t] = y[k];
}

// merge: y = relu(b + msg_own @ W[0:64] + msg_partner @ W[64:128]); partner = t^1 column.
__device__ __forceinline__ void merge_lds(const float* __restrict__ W, const float* __restrict__ b,
                                          lds_t* xs, int t, float (&y)[64]) {
#pragma unroll
  for (int c = 0; c < 64; ++c) y[c] = b[c];
#pragma unroll 2
  for (int k = 0; k < 64; ++k) {
    float xk = xs[k][t];
    const float* wr = W + k * 64;
#pragma unroll
    for (int c = 0; c < 64; ++c) y[c] = fmaf(xk, wr[c], y[c]);
  }
#pragma unroll 2
  for (int k = 0; k < 64; ++k) {
    float xk = xs[k][t ^ 1];  // flip: partner edge's msg
    const float* wr = W + (64 + k) * 64;
#pragma unroll
    for (int c = 0; c < 64; ++c) y[c] = fmaf(xk, wr[c], y[c]);
  }
#pragma unroll
  for (int c = 0; c < 64; ++c) y[c] = fmaxf(y[c], 0.f);
}

// ---- l2c branch: 3-layer MLP -> pair merge -> 2-layer MLP ----
__global__ void __launch_bounds__(256, 4)
k_l2c(const int* __restrict__ ei, const int* __restrict__ l2ci,
      const float* __restrict__ emb, const float* __restrict__ aggr,
      const float* __restrict__ W, const float* __restrict__ bb,
      const float* __restrict__ mW0, const float* __restrict__ mb0,
      const float* __restrict__ mW, const float* __restrict__ mb,
      float* __restrict__ out) {
  __shared__ float xs[64][256];
  int t = threadIdx.x;
  int r = blockIdx.x * 256 + t;
  int rc = r < HEDGE ? r : HEDGE - 1;  // tail threads compute garbage but keep barriers
  int j = l2ci[rc];
  int s = ei[2 * j], d = ei[2 * j + 1];
  const float4* ap = (const float4*)(aggr + (size_t)s * 64);
  const float4* ep = (const float4*)(emb + (size_t)d * 64);
#pragma unroll
  for (int q = 0; q < 16; ++q) {
    float4 a = ap[q], e = ep[q];
    xs[4 * q + 0][t] = a.x - e.x;
    xs[4 * q + 1][t] = a.y - e.y;
    xs[4 * q + 2][t] = a.z - e.z;
    xs[4 * q + 3][t] = a.w - e.w;
  }
  float y[64];
  layer_lds<true>(W, bb, xs, t, y);            commit(xs, t, y);
  layer_lds<true>(W + 4096, bb + 64, xs, t, y); commit(xs, t, y);
  layer_lds<false>(W + 8192, bb + 128, xs, t, y); commit(xs, t, y);  // msg
  __syncthreads();               // partner column must be written before flip reads
  merge_lds(mW0, mb0, xs, t, y);
  __syncthreads();               // flip reads done before overwriting columns
  commit(xs, t, y);
  layer_lds<true>(mW, mb, xs, t, y);           commit(xs, t, y);
  layer_lds<false>(mW + 4096, mb + 64, xs, t, y);
  if (r < HEDGE) {
    float4* op = (float4*)(out + (size_t)j * 64);
#pragma unroll
    for (int q = 0; q < 16; ++q) {
      float4 v;
      v.x = y[4 * q + 0]; v.y = y[4 * q + 1]; v.z = y[4 * q + 2]; v.w = y[4 * q + 3];
      op[q] = v;
    }
  }
}

// ---- c2l branch: 3-layer MLP on (lse[src] - e) ----
__global__ void __launch_bounds__(256, 4)
k_c2l(const int* __restrict__ ei, const int* __restrict__ c2li,
      const float* __restrict__ emb, const float* __restrict__ lse,
      const float* __restrict__ W, const float* __restrict__ bb,
      float* __restrict__ out) {
  __shared__ float xs[64][256];
  int t = threadIdx.x;
  int r = blockIdx.x * 256 + t;
  if (r >= HEDGE) return;  // no cross-thread LDS use here, safe
  int j = c2li[r];
  int s = ei[2 * j], d = ei[2 * j + 1];
  const float4* lp = (const float4*)(lse + (size_t)s * 64);
  const float4* ep = (const float4*)(emb + (size_t)d * 64);
#pragma unroll
  for (int q = 0; q < 16; ++q) {
    float4 a = lp[q], e = ep[q];
    xs[4 * q + 0][t] = a.x - e.x;
    xs[4 * q + 1][t] = a.y - e.y;
    xs[4 * q + 2][t] = a.z - e.z;
    xs[4 * q + 3][t] = a.w - e.w;
  }
  float y[64];
  layer_lds<true>(W, bb, xs, t, y);             commit(xs, t, y);
  layer_lds<true>(W + 4096, bb + 64, xs, t, y); commit(xs, t, y);
  layer_lds<false>(W + 8192, bb + 128, xs, t, y);
  float4* op = (float4*)(out + (size_t)j * 64);
#pragma unroll
  for (int q = 0; q < 16; ++q) {
    float4 v;
    v.x = y[4 * q + 0]; v.y = y[4 * q + 1]; v.z = y[4 * q + 2]; v.w = y[4 * q + 3];
    op[q] = v;
  }
}

extern "C" void kernel_launch(void* const* d_in, const int* in_sizes, int n_in,
                              void* d_out, int out_size, void* d_ws, size_t ws_size,
                              hipStream_t stream) {
  const int* ei = (const int*)d_in[0];
  const int* l2ci = (const int*)d_in[1];
  const int* c2li = (const int*)d_in[2];
  const float* emb = (const float*)d_in[3];
  const float* l2cW = (const float*)d_in[4];
  const float* l2cb = (const float*)d_in[5];
  const float* c2lW = (const float*)d_in[6];
  const float* c2lb = (const float*)d_in[7];
  const float* mW0 = (const float*)d_in[8];
  const float* mb0 = (const float*)d_in[9];
  const float* mW = (const float*)d_in[10];
  const float* mb = (const float*)d_in[11];
  float* out = (float*)d_out;

  char* ws = (char*)d_ws;
  const size_t NB = (size_t)NNODE * 64 * 4;  // 51.2 MB per node-buffer
  float* aggr = (float*)ws;
  unsigned* mkey = (unsigned*)(ws + NB);
  float* ssum = (float*)(ws + 2 * NB);  // becomes lse in-place

  hipMemsetAsync(d_ws, 0, 3 * NB, stream);  // aggr=0, mkey=0 (== -inf key), ssum=0

  dim3 B(256);
  k_aggr<<<(NEDGE * 64 + 255) / 256, B, 0, stream>>>(ei, emb, aggr);
  k_cmax<<<(HEDGE * 64 + 255) / 256, B, 0, stream>>>(ei, c2li, emb, mkey);
  k_cexp<<<(HEDGE * 64 + 255) / 256, B, 0, stream>>>(ei, c2li, emb, mkey, ssum);
  k_lse<<<(NNODE * 64 + 255) / 256, B, 0, stream>>>(mkey, ssum);
  k_l2c<<<(HEDGE + 255) / 256, B, 0, stream>>>(ei, l2ci, emb, aggr, l2cW, l2cb, mW0, mb0, mW, mb, out);
  k_c2l<<<(HEDGE + 255) / 256, B, 0, stream>>>(ei, c2li, emb, ssum, c2lW, c2lb, out);
}

// Round 4
// 827.354 us; speedup vs baseline: 4.1054x; 1.6929x over previous
//
#include <hip/hip_runtime.h>
#include <math.h>

#define NNODE 200000
#define NEDGE 1000000
#define HEDGE 500000

typedef __attribute__((ext_vector_type(8))) short bf16x8;
typedef __attribute__((ext_vector_type(4))) float f32x4;

// ---- float <-> bf16 (RNE) without relying on hip_bf16 API ----
__device__ __forceinline__ unsigned short f2bf(float f) {
  unsigned u = __float_as_uint(f);
  unsigned r = (u + 0x7fffu + ((u >> 16) & 1u)) >> 16;
  return (unsigned short)r;
}
__device__ __forceinline__ float bf2f(unsigned short h) {
  return __uint_as_float(((unsigned)h) << 16);
}

// ---- float <-> monotone uint key (for atomicMax on floats) ----
__device__ __forceinline__ unsigned fkey(float f) {
  unsigned b = __float_as_uint(f);
  return (b & 0x80000000u) ? ~b : (b | 0x80000000u);
}
__device__ __forceinline__ float funkey(unsigned k) {
  unsigned b = (k & 0x80000000u) ? (k ^ 0x80000000u) : ~k;
  return __uint_as_float(b);
}

// ======================= aux (segment ops) =======================
__global__ void k_aggr(const int* __restrict__ ei, const float* __restrict__ emb,
                       float* __restrict__ aggr) {
  int tid = blockIdx.x * 256 + threadIdx.x;
  if (tid >= NEDGE * 64) return;
  int e = tid >> 6, c = tid & 63;
  int d = ei[2 * e + 1];
  atomicAdd(&aggr[d * 64 + c], emb[tid]);
}

__global__ void k_cmax(const int* __restrict__ ei, const int* __restrict__ c2li,
                       const float* __restrict__ emb, unsigned* __restrict__ mkey) {
  int tid = blockIdx.x * 256 + threadIdx.x;
  if (tid >= HEDGE * 64) return;
  int i = tid >> 6, c = tid & 63;
  int j = c2li[i];
  int s = ei[2 * j], d = ei[2 * j + 1];
  float v = emb[d * 64 + c];
  atomicMax(&mkey[s * 64 + c], fkey(v));
}

__global__ void k_cexp(const int* __restrict__ ei, const int* __restrict__ c2li,
                       const float* __restrict__ emb, const unsigned* __restrict__ mkey,
                       float* __restrict__ ssum) {
  int tid = blockIdx.x * 256 + threadIdx.x;
  if (tid >= HEDGE * 64) return;
  int i = tid >> 6, c = tid & 63;
  int j = c2li[i];
  int s = ei[2 * j], d = ei[2 * j + 1];
  float v = emb[d * 64 + c];
  float m = funkey(mkey[s * 64 + c]);
  atomicAdd(&ssum[s * 64 + c], expf(v - m));
}

__global__ void k_lse(const unsigned* __restrict__ mkey, float* __restrict__ ssum) {
  int tid = blockIdx.x * 256 + threadIdx.x;
  if (tid >= NNODE * 64) return;
  unsigned k = mkey[tid];
  float ss = ssum[tid];
  float m = (k == 0u) ? 0.f : funkey(k);
  float l = (ss > 0.f) ? logf(ss) : 0.f;
  ssum[tid] = l + m;
}

// ======================= weight prep =======================
// Frag-ordered bf16 hi/lo. Elem layout per matrix: [(s*4+c)*64 + lane]*8 + j,
// value = W[32s + 8*(lane>>4) + j][16c + (lane&15)].
// Elem offsets: l2c L1/L2/L3: 0/4096/8192; merge_W0: 12288 (K=128);
// merge_W L1/L2: 20480/24576; c2l L1/L2/L3: 28672/32768/36864. Total 40960.
__global__ void k_prepw(const float* __restrict__ l2cW, const float* __restrict__ mW0,
                        const float* __restrict__ mW, const float* __restrict__ c2lW,
                        unsigned short* __restrict__ WH, unsigned short* __restrict__ WL) {
  int tid = blockIdx.x * 256 + threadIdx.x;
  if (tid >= 40960) return;
  const float* src;
  int base;
  if (tid < 12288) {
    int m = tid / 4096; src = l2cW + m * 4096; base = m * 4096;
  } else if (tid < 20480) {
    src = mW0; base = 12288;
  } else if (tid < 28672) {
    int m = (tid - 20480) / 4096; src = mW + m * 4096; base = 20480 + m * 4096;
  } else {
    int m = (tid - 28672) / 4096; src = c2lW + m * 4096; base = 28672 + m * 4096;
  }
  int local = tid - base;
  int f = local >> 9;           // frag id = s*4+c
  int l = (local >> 3) & 63;    // lane
  int j = local & 7;            // elem
  int s = f >> 2, c = f & 3;
  int k = 32 * s + 8 * (l >> 4) + j;
  int col = 16 * c + (l & 15);
  float v = src[k * 64 + col];
  unsigned short hh = f2bf(v);
  WH[tid] = hh;
  WL[tid] = f2bf(v - bf2f(hh));
}

// ======================= MFMA MLP machinery =======================
// Wave-private LDS tile xs[16 rows][64 cols] f32, XOR-swizzled:
//   dword(row,col) = row*64 + (((col>>2) ^ row) & 15)*4 + (col & 3)
// so stride-256B ds_read_b128 A-frag reads are bank-conflict-free.

__device__ __forceinline__ void split8(float t0, float t1, float t2, float t3,
                                       float t4, float t5, float t6, float t7,
                                       bf16x8& ah, bf16x8& al) {
  unsigned short h;
  h = f2bf(t0); ah[0] = (short)h; al[0] = (short)f2bf(t0 - bf2f(h));
  h = f2bf(t1); ah[1] = (short)h; al[1] = (short)f2bf(t1 - bf2f(h));
  h = f2bf(t2); ah[2] = (short)h; al[2] = (short)f2bf(t2 - bf2f(h));
  h = f2bf(t3); ah[3] = (short)h; al[3] = (short)f2bf(t3 - bf2f(h));
  h = f2bf(t4); ah[4] = (short)h; al[4] = (short)f2bf(t4 - bf2f(h));
  h = f2bf(t5); ah[5] = (short)h; al[5] = (short)f2bf(t5 - bf2f(h));
  h = f2bf(t6); ah[6] = (short)h; al[6] = (short)f2bf(t6 - bf2f(h));
  h = f2bf(t7); ah[7] = (short)h; al[7] = (short)f2bf(t7 - bf2f(h));
}

// One dense layer on the matrix pipe. NS = K/32 slices. FLIP: second half of
// slices reads the partner row (row^1) = pair-flip for the merge layer.
// Split-bf16: acc += al*wh + ah*wl + ah*wh  (misses only lo*lo ~ 2^-18).
template <int NS, bool RELU, bool FLIP>
__device__ __forceinline__ void mfma_layer(const float* xw, int lane,
                                           const unsigned short* __restrict__ wh_,
                                           const unsigned short* __restrict__ wl_,
                                           const float* __restrict__ bias, f32x4 (&acc)[4]) {
  int col15 = lane & 15, hq = lane >> 4;
#pragma unroll
  for (int c = 0; c < 4; ++c) {
    float bv = bias[16 * c + col15];
    acc[c] = (f32x4){bv, bv, bv, bv};
  }
#pragma unroll
  for (int s = 0; s < NS; ++s) {
    int flip = (FLIP && s >= NS / 2);
    int arow = flip ? (col15 ^ 1) : col15;
    int ks = flip ? (s - NS / 2) : s;
    const float* xr = xw + arow * 64;
    float4 A0 = *(const float4*)(xr + ((((8 * ks + 2 * hq + 0) ^ arow) & 15) << 2));
    float4 A1 = *(const float4*)(xr + ((((8 * ks + 2 * hq + 1) ^ arow) & 15) << 2));
    bf16x8 ah, al;
    split8(A0.x, A0.y, A0.z, A0.w, A1.x, A1.y, A1.z, A1.w, ah, al);
#pragma unroll
    for (int c = 0; c < 4; ++c) {
      const unsigned short* wo = wh_ + ((size_t)((s * 4 + c) * 64 + lane) * 8);
      const unsigned short* lo = wl_ + ((size_t)((s * 4 + c) * 64 + lane) * 8);
      bf16x8 wh = *(const bf16x8*)wo;
      bf16x8 wl = *(const bf16x8*)lo;
      acc[c] = __builtin_amdgcn_mfma_f32_16x16x32_bf16(al, wh, acc[c], 0, 0, 0);
      acc[c] = __builtin_amdgcn_mfma_f32_16x16x32_bf16(ah, wl, acc[c], 0, 0, 0);
      acc[c] = __builtin_amdgcn_mfma_f32_16x16x32_bf16(ah, wh, acc[c], 0, 0, 0);
    }
  }
  if (RELU) {
#pragma unroll
    for (int c = 0; c < 4; ++c)
#pragma unroll
      for (int r = 0; r < 4; ++r) acc[c][r] = fmaxf(acc[c][r], 0.f);
  }
}

// D (row=4*hq+r, col=16c+col15) -> swizzled LDS
__device__ __forceinline__ void commitA(float* xw, int lane, const f32x4 (&acc)[4]) {
  int col15 = lane & 15, hq = lane >> 4;
#pragma unroll
  for (int c = 0; c < 4; ++c)
#pragma unroll
    for (int r = 0; r < 4; ++r) {
      int row = 4 * hq + r, col = 16 * c + col15;
      xw[row * 64 + ((((col >> 2) ^ row) & 15) << 2) + (col & 3)] = acc[c][r];
    }
}

// ---- l2c: 3-layer MLP -> pair merge (K=128, flip) -> 2-layer MLP ----
__global__ void __launch_bounds__(256, 4)
k_l2c(const int* __restrict__ ei, const int* __restrict__ l2ci,
      const float* __restrict__ emb, const float* __restrict__ aggr,
      const unsigned short* __restrict__ WH, const unsigned short* __restrict__ WL,
      const float* __restrict__ l2cb, const float* __restrict__ mb0,
      const float* __restrict__ mb, float* __restrict__ out) {
  __shared__ float xs[4][1024];
  int lane = threadIdx.x & 63, w = threadIdx.x >> 6;
  float* xw = xs[w];
  int rbase = (blockIdx.x * 4 + w) * 16;
  int col15 = lane & 15, hq = lane >> 4;
  int rin = min(rbase + col15, HEDGE - 1);
  int j = l2ci[rin];
  int sN = ei[2 * j], dN = ei[2 * j + 1];
  const float* ap = aggr + (size_t)sN * 64 + 16 * hq;
  const float* ep = emb + (size_t)dN * 64 + 16 * hq;
#pragma unroll
  for (int q = 0; q < 4; ++q) {
    float4 a = *(const float4*)(ap + 4 * q);
    float4 e = *(const float4*)(ep + 4 * q);
    float4 v = {a.x - e.x, a.y - e.y, a.z - e.z, a.w - e.w};
    *(float4*)(xw + col15 * 64 + ((((4 * hq + q) ^ col15) & 15) << 2)) = v;
  }
  f32x4 acc[4];
  mfma_layer<2, true, false>(xw, lane, WH, WL, l2cb, acc);                     commitA(xw, lane, acc);
  mfma_layer<2, true, false>(xw, lane, WH + 4096, WL + 4096, l2cb + 64, acc);  commitA(xw, lane, acc);
  mfma_layer<2, false, false>(xw, lane, WH + 8192, WL + 8192, l2cb + 128, acc); commitA(xw, lane, acc);
  mfma_layer<4, true, true>(xw, lane, WH + 12288, WL + 12288, mb0, acc);       commitA(xw, lane, acc);
  mfma_layer<2, true, false>(xw, lane, WH + 20480, WL + 20480, mb, acc);       commitA(xw, lane, acc);
  mfma_layer<2, false, false>(xw, lane, WH + 24576, WL + 24576, mb + 64, acc);
  int jo[4];
#pragma unroll
  for (int r = 0; r < 4; ++r) {
    int rr = rbase + 4 * hq + r;
    jo[r] = (rr < HEDGE) ? l2ci[rr] : -1;
  }
#pragma unroll
  for (int c = 0; c < 4; ++c)
#pragma unroll
    for (int r = 0; r < 4; ++r)
      if (jo[r] >= 0) out[(size_t)jo[r] * 64 + 16 * c + col15] = acc[c][r];
}

// ---- c2l: 3-layer MLP on (lse[src] - e) ----
__global__ void __launch_bounds__(256, 4)
k_c2l(const int* __restrict__ ei, const int* __restrict__ c2li,
      const float* __restrict__ emb, const float* __restrict__ lse,
      const unsigned short* __restrict__ WH, const unsigned short* __restrict__ WL,
      const float* __restrict__ c2lb, float* __restrict__ out) {
  __shared__ float xs[4][1024];
  int lane = threadIdx.x & 63, w = threadIdx.x >> 6;
  float* xw = xs[w];
  int rbase = (blockIdx.x * 4 + w) * 16;
  int col15 = lane & 15, hq = lane >> 4;
  int rin = min(rbase + col15, HEDGE - 1);
  int j = c2li[rin];
  int sN = ei[2 * j], dN = ei[2 * j + 1];
  const float* ap = lse + (size_t)sN * 64 + 16 * hq;
  const float* ep = emb + (size_t)dN * 64 + 16 * hq;
#pragma unroll
  for (int q = 0; q < 4; ++q) {
    float4 a = *(const float4*)(ap + 4 * q);
    float4 e = *(const float4*)(ep + 4 * q);
    float4 v = {a.x - e.x, a.y - e.y, a.z - e.z, a.w - e.w};
    *(float4*)(xw + col15 * 64 + ((((4 * hq + q) ^ col15) & 15) << 2)) = v;
  }
  f32x4 acc[4];
  mfma_layer<2, true, false>(xw, lane, WH + 28672, WL + 28672, c2lb, acc);       commitA(xw, lane, acc);
  mfma_layer<2, true, false>(xw, lane, WH + 32768, WL + 32768, c2lb + 64, acc);  commitA(xw, lane, acc);
  mfma_layer<2, false, false>(xw, lane, WH + 36864, WL + 36864, c2lb + 128, acc);
  int jo[4];
#pragma unroll
  for (int r = 0; r < 4; ++r) {
    int rr = rbase + 4 * hq + r;
    jo[r] = (rr < HEDGE) ? c2li[rr] : -1;
  }
#pragma unroll
  for (int c = 0; c < 4; ++c)
#pragma unroll
    for (int r = 0; r < 4; ++r)
      if (jo[r] >= 0) out[(size_t)jo[r] * 64 + 16 * c + col15] = acc[c][r];
}

extern "C" void kernel_launch(void* const* d_in, const int* in_sizes, int n_in,
                              void* d_out, int out_size, void* d_ws, size_t ws_size,
                              hipStream_t stream) {
  const int* ei = (const int*)d_in[0];
  const int* l2ci = (const int*)d_in[1];
  const int* c2li = (const int*)d_in[2];
  const float* emb = (const float*)d_in[3];
  const float* l2cW = (const float*)d_in[4];
  const float* l2cb = (const float*)d_in[5];
  const float* c2lW = (const float*)d_in[6];
  const float* c2lb = (const float*)d_in[7];
  const float* mW0 = (const float*)d_in[8];
  const float* mb0 = (const float*)d_in[9];
  const float* mW = (const float*)d_in[10];
  const float* mb = (const float*)d_in[11];
  float* out = (float*)d_out;

  char* ws = (char*)d_ws;
  const size_t NB = (size_t)NNODE * 64 * 4;  // 51.2 MB per node-buffer
  float* aggr = (float*)ws;
  unsigned* mkey = (unsigned*)(ws + NB);   // freed after k_lse -> reused for weights
  float* ssum = (float*)(ws + 2 * NB);     // becomes lse in-place
  unsigned short* WH = (unsigned short*)(ws + NB);
  unsigned short* WL = WH + 40960;         // 160 KB total, inside the mkey region

  hipMemsetAsync(d_ws, 0, 3 * NB, stream);  // aggr=0, mkey=0 (== -inf key), ssum=0

  dim3 B(256);
  k_aggr<<<(NEDGE * 64 + 255) / 256, B, 0, stream>>>(ei, emb, aggr);
  k_cmax<<<(HEDGE * 64 + 255) / 256, B, 0, stream>>>(ei, c2li, emb, mkey);
  k_cexp<<<(HEDGE * 64 + 255) / 256, B, 0, stream>>>(ei, c2li, emb, mkey, ssum);
  k_lse<<<(NNODE * 64 + 255) / 256, B, 0, stream>>>(mkey, ssum);
  k_prepw<<<160, B, 0, stream>>>(l2cW, mW0, mW, c2lW, WH, WL);  // mkey region now free
  int gmlp = (HEDGE / 16 + 3) / 4;
  k_l2c<<<gmlp, B, 0, stream>>>(ei, l2ci, emb, aggr, WH, WL, l2cb, mb0, mb, out);
  k_c2l<<<gmlp, B, 0, stream>>>(ei, c2li, emb, ssum, WH, WL, c2lb, out);
}